// Round 1
// baseline (481.210 us; speedup 1.0000x reference)
//
#include <hip/hip_runtime.h>

#define NPX (2160*3840)

// ---------------- resize along W: (3,2160,3840) -> (3,2160,256) ----------------
// jax.image.resize bilinear antialias: scale=256/3840=1/15, sample_f = 15*i+7 (exact int),
// weight(j) = max(0, 1-|sf-j|/15), normalized. Integer weights (15-d), normalize by sum.
__global__ void resize_w_kernel(const float* __restrict__ img, float* __restrict__ tmp) {
  __shared__ __align__(16) float row[3840];
  const int bh = blockIdx.x;            // c*2160 + h
  const float* src = img + (size_t)bh * 3840;
  const int tid = threadIdx.x;          // 256
  const float4* s4 = (const float4*)src;
  float4* r4 = (float4*)row;
  for (int i = tid; i < 960; i += 256) r4[i] = s4[i];
  __syncthreads();
  const int i = tid;
  const int center = 15*i + 7;
  int lo = center - 14; if (lo < 0) lo = 0;
  int hi = center + 14; if (hi > 3839) hi = 3839;
  float acc = 0.f, wsum = 0.f;
  for (int j = lo; j <= hi; ++j) {
    int d = center - j; d = d < 0 ? -d : d;
    float w = (float)(15 - d);
    acc += w * row[j];
    wsum += w;
  }
  tmp[bh*256 + i] = acc / wsum;
}

// ---------------- resize along H: (3,2160,256) -> (3,256,256) ----------------
// scale=256/2160, inv_scale=8.4375, kernel_scale=8.4375; w=max(0,1-|sf-j|*16/135), normalized.
__global__ void resize_h_kernel(const float* __restrict__ tmp, float* __restrict__ dst) {
  const int c = blockIdx.x >> 8;
  const int oh = blockIdx.x & 255;
  const int ow = threadIdx.x;           // 256
  const float sf = ((float)oh + 0.5f) * 8.4375f - 0.5f;
  int lo = (int)ceilf(sf - 8.4375f); if (lo < 0) lo = 0;
  int hi = (int)floorf(sf + 8.4375f); if (hi > 2159) hi = 2159;
  float acc = 0.f, wsum = 0.f;
  for (int j = lo; j <= hi; ++j) {
    float w = 1.f - fabsf(sf - (float)j) * (16.f/135.f);
    if (w > 0.f) {
      acc += w * tmp[(c*2160 + j)*256 + ow];
      wsum += w;
    }
  }
  dst[blockIdx.x*256 + ow] = acc / wsum;
}

// ---------------- fused conv3x3(stride2,pad1) + bias + lrelu + (instance norm) ----------------
// One block per output channel; per-thread accumulators in registers (static indexing only);
// two-pass mean/var to match jnp.var.
template<int TPB,int CIN,int HIN,int WIN,int HOUT,int WOUT,bool NORM>
__global__ __launch_bounds__(TPB) void conv_block(const float* __restrict__ in,
    const float* __restrict__ wt, const float* __restrict__ bias,
    const float* __restrict__ gam, const float* __restrict__ bet,
    float* __restrict__ out) {
  constexpr int HW = HOUT*WOUT;
  constexpr int PER = (HW + TPB - 1)/TPB;
  const int co = blockIdx.x;
  const int tid = threadIdx.x;
  __shared__ float wl[CIN*9];
  __shared__ float red[TPB];
  for (int i = tid; i < CIN*9; i += TPB) wl[i] = wt[co*CIN*9 + i];
  __syncthreads();
  const float bco = bias[co];
  float acc[PER];
  #pragma unroll
  for (int p = 0; p < PER; ++p) {
    const int idx = p*TPB + tid;
    float v = 0.f;
    if (idx < HW) {
      const int oh = idx / WOUT;
      const int ow = idx - oh*WOUT;
      float s = bco;
      const int ih0 = oh*2 - 1, iw0 = ow*2 - 1;
      for (int ci = 0; ci < CIN; ++ci) {
        const float* ip = in + ci*HIN*WIN;
        const float* wp = wl + ci*9;
        #pragma unroll
        for (int kh = 0; kh < 3; ++kh) {
          const int ih = ih0 + kh;
          if (ih < 0 || ih >= HIN) continue;
          #pragma unroll
          for (int kw = 0; kw < 3; ++kw) {
            const int iw = iw0 + kw;
            if (iw < 0 || iw >= WIN) continue;
            s += ip[ih*WIN + iw] * wp[kh*3 + kw];
          }
        }
      }
      v = s >= 0.f ? s : 0.2f*s;
    }
    acc[p] = v;
  }
  if constexpr (NORM) {
    float ls = 0.f;
    #pragma unroll
    for (int p = 0; p < PER; ++p) ls += acc[p];
    red[tid] = ls;
    __syncthreads();
    for (int s = TPB/2; s > 0; s >>= 1) {
      if (tid < s) red[tid] += red[tid + s];
      __syncthreads();
    }
    const float mean = red[0] * (1.f/HW);
    __syncthreads();
    float lv = 0.f;
    #pragma unroll
    for (int p = 0; p < PER; ++p) {
      const int idx = p*TPB + tid;
      if (idx < HW) { const float d = acc[p] - mean; lv += d*d; }
    }
    red[tid] = lv;
    __syncthreads();
    for (int s = TPB/2; s > 0; s >>= 1) {
      if (tid < s) red[tid] += red[tid + s];
      __syncthreads();
    }
    const float var = red[0] * (1.f/HW);
    const float sc = rsqrtf(var + 1e-5f) * gam[co];
    const float sh = bet[co];
    #pragma unroll
    for (int p = 0; p < PER; ++p) {
      const int idx = p*TPB + tid;
      if (idx < HW) out[co*HW + idx] = (acc[p] - mean)*sc + sh;
    }
  } else {
    #pragma unroll
    for (int p = 0; p < PER; ++p) {
      const int idx = p*TPB + tid;
      if (idx < HW) out[co*HW + idx] = acc[p];
    }
  }
}

// ---------------- conv6: (128,8,8) . (3,128,8,8) + b -> pred[3], no activation ----------------
__global__ void conv6_kernel(const float* __restrict__ in, const float* __restrict__ wt,
                             const float* __restrict__ bias, float* __restrict__ pred) {
  __shared__ float red[256];
  const int tid = threadIdx.x;
  for (int co = 0; co < 3; ++co) {
    float s = 0.f;
    for (int e = tid; e < 8192; e += 256) s += in[e] * wt[co*8192 + e];
    red[tid] = s;
    __syncthreads();
    for (int k = 128; k > 0; k >>= 1) {
      if (tid < k) red[tid] += red[tid + k];
      __syncthreads();
    }
    if (tid == 0) pred[co] = red[0] + bias[co];
    __syncthreads();
  }
}

// ---------------- final LUT blend: fl = p0*lut0 + p1*lut1 + p2*lut2 (3*33^3) ----------------
__global__ void final_lut_kernel(const float* __restrict__ l0, const float* __restrict__ l1,
                                 const float* __restrict__ l2, const float* __restrict__ pred,
                                 float* __restrict__ fl) {
  const int i = blockIdx.x*256 + threadIdx.x;
  if (i < 3*35937) fl[i] = pred[0]*l0[i] + pred[1]*l1[i] + pred[2]*l2[i];
}

// ---------------- trilinear apply: per-channel LUT staged in LDS (143.7 KB) ----------------
__global__ __launch_bounds__(1024) void trilinear_kernel(const float* __restrict__ img,
    const float* __restrict__ fl, float* __restrict__ out) {
  __shared__ float slut[35937];
  const int tid = threadIdx.x;
  const int p0 = blockIdx.x * 32400;     // 256 blocks * 32400 = 8,294,400 exactly
  const int p1 = p0 + 32400;
  for (int c = 0; c < 3; ++c) {
    for (int i = tid; i < 35937; i += 1024) slut[i] = fl[c*35937 + i];
    __syncthreads();
    for (int p = p0 + tid; p < p1; p += 1024) {
      const float r = img[p];
      const float g = img[NPX + p];
      const float b = img[2*NPX + p];
      const float xr = r*32.f, xg = g*32.f, xb = b*32.f;
      int ir = (int)floorf(xr); ir = ir < 0 ? 0 : (ir > 31 ? 31 : ir);
      int ig = (int)floorf(xg); ig = ig < 0 ? 0 : (ig > 31 ? 31 : ig);
      int ib = (int)floorf(xb); ib = ib < 0 ? 0 : (ib > 31 ? 31 : ib);
      const float fr = xr - (float)ir;
      const float fg = xg - (float)ig;
      const float fb = xb - (float)ib;
      const int base = (ib*33 + ig)*33 + ir;
      const float v000 = slut[base],      v001 = slut[base+1];
      const float v010 = slut[base+33],   v011 = slut[base+34];
      const float v100 = slut[base+1089], v101 = slut[base+1090];
      const float v110 = slut[base+1122], v111 = slut[base+1123];
      const float wr0 = 1.f - fr;
      const float wg0 = 1.f - fg;
      const float wb0 = 1.f - fb;
      const float lo = wg0*(v000*wr0 + v001*fr) + fg*(v010*wr0 + v011*fr);
      const float hi = wg0*(v100*wr0 + v101*fr) + fg*(v110*wr0 + v111*fr);
      out[c*NPX + p] = wb0*lo + fb*hi;
    }
    __syncthreads();
  }
}

extern "C" void kernel_launch(void* const* d_in, const int* in_sizes, int n_in,
                              void* d_out, int out_size, void* d_ws, size_t ws_size,
                              hipStream_t stream) {
  const float* img  = (const float*)d_in[0];
  const float* lut0 = (const float*)d_in[1];
  const float* lut1 = (const float*)d_in[2];
  const float* lut2 = (const float*)d_in[3];
  const float* w1 = (const float*)d_in[4];  const float* b1  = (const float*)d_in[5];
  const float* g1 = (const float*)d_in[6];  const float* be1 = (const float*)d_in[7];
  const float* w2 = (const float*)d_in[8];  const float* b2  = (const float*)d_in[9];
  const float* g2 = (const float*)d_in[10]; const float* be2 = (const float*)d_in[11];
  const float* w3 = (const float*)d_in[12]; const float* b3  = (const float*)d_in[13];
  const float* g3 = (const float*)d_in[14]; const float* be3 = (const float*)d_in[15];
  const float* w4 = (const float*)d_in[16]; const float* b4  = (const float*)d_in[17];
  const float* g4 = (const float*)d_in[18]; const float* be4 = (const float*)d_in[19];
  const float* w5 = (const float*)d_in[20]; const float* b5  = (const float*)d_in[21];
  const float* w6 = (const float*)d_in[22]; const float* b6  = (const float*)d_in[23];

  float* ws = (float*)d_ws;
  // layout (floats): tmp [0, 1658880) lives only until resize_h; conv buffers reuse it.
  float* tmp  = ws;                  // 3*2160*256 = 1,658,880
  float* r256 = ws + 1658880;        // 3*256*256 = 196,608   (peak ws use ~7.5 MB)
  float* c1   = ws;                  // 16*128*128 = 262,144 (tmp dead by now)
  float* c2   = ws + 262144;         // 32*64*64  = 131,072
  float* c3   = ws + 393216;         // 64*32*32  =  65,536
  float* c4   = ws + 458752;         // 128*16*16 =  32,768
  float* c5   = ws + 491520;         // 128*8*8   =   8,192
  float* pred = ws + 499712;         // 3 (pad 4)
  float* flut = ws + 499716;         // 3*35937 = 107,811

  resize_w_kernel<<<3*2160, 256, 0, stream>>>(img, tmp);
  resize_h_kernel<<<3*256, 256, 0, stream>>>(tmp, r256);
  conv_block<1024,  3,256,256,128,128,true ><<< 16,1024,0,stream>>>(r256, w1,b1,g1,be1, c1);
  conv_block<1024, 16,128,128, 64, 64,true ><<< 32,1024,0,stream>>>(c1,   w2,b2,g2,be2, c2);
  conv_block<1024, 32, 64, 64, 32, 32,true ><<< 64,1024,0,stream>>>(c2,   w3,b3,g3,be3, c3);
  conv_block< 256, 64, 32, 32, 16, 16,true ><<<128, 256,0,stream>>>(c3,   w4,b4,g4,be4, c4);
  conv_block< 256,128, 16, 16,  8,  8,false><<<128, 256,0,stream>>>(c4,   w5,b5,nullptr,nullptr, c5);
  conv6_kernel<<<1, 256, 0, stream>>>(c5, w6, b6, pred);
  final_lut_kernel<<<422, 256, 0, stream>>>(lut0, lut1, lut2, pred, flut);
  trilinear_kernel<<<256, 1024, 0, stream>>>(img, flut, (float*)d_out);
}

// Round 2
// 393.099 us; speedup vs baseline: 1.2241x; 1.2241x over previous
//
#include <hip/hip_runtime.h>

#define NPX (2160*3840)

// ---------------- resize along W: (3,2160,3840) -> (3,2160,256) ----------------
// jax.image.resize bilinear antialias: scale=1/15, sample_f = 15*i+7 (exact int),
// weight(j) = max(0, 15-|sf-j|)/15, normalized by sum.
__global__ void resize_w_kernel(const float* __restrict__ img, float* __restrict__ tmp) {
  __shared__ __align__(16) float row[3840];
  const int bh = blockIdx.x;            // c*2160 + h
  const float* src = img + (size_t)bh * 3840;
  const int tid = threadIdx.x;          // 256
  const float4* s4 = (const float4*)src;
  float4* r4 = (float4*)row;
  for (int i = tid; i < 960; i += 256) r4[i] = s4[i];
  __syncthreads();
  const int i = tid;
  const int center = 15*i + 7;
  int lo = center - 14; if (lo < 0) lo = 0;
  int hi = center + 14; if (hi > 3839) hi = 3839;
  float acc = 0.f, wsum = 0.f;
  for (int j = lo; j <= hi; ++j) {
    int d = center - j; d = d < 0 ? -d : d;
    float w = (float)(15 - d);
    acc += w * row[j];
    wsum += w;
  }
  tmp[bh*256 + i] = acc / wsum;
}

// ---------------- resize along H: (3,2160,256) -> (3,256,256) ----------------
__global__ void resize_h_kernel(const float* __restrict__ tmp, float* __restrict__ dst) {
  const int c = blockIdx.x >> 8;
  const int oh = blockIdx.x & 255;
  const int ow = threadIdx.x;           // 256
  const float sf = ((float)oh + 0.5f) * 8.4375f - 0.5f;
  int lo = (int)ceilf(sf - 8.4375f); if (lo < 0) lo = 0;
  int hi = (int)floorf(sf + 8.4375f); if (hi > 2159) hi = 2159;
  float acc = 0.f, wsum = 0.f;
  for (int j = lo; j <= hi; ++j) {
    float w = 1.f - fabsf(sf - (float)j) * (16.f/135.f);
    if (w > 0.f) {
      acc += w * tmp[(c*2160 + j)*256 + ow];
      wsum += w;
    }
  }
  dst[blockIdx.x*256 + ow] = acc / wsum;
}

// ---------------- direct conv3x3(stride2,pad1) + bias + lrelu ----------------
// Grid = (CO/COPB) * NBLK spatial tiles; 256 threads; one output pixel per thread.
// Interior fast path (only oh==0 / ow==0 rows are boundary for stride2/pad1).
template<int CIN,int HIN,int WIN,int HOUT,int WOUT,int COPB,bool LRELU>
__global__ __launch_bounds__(256) void conv_direct(const float* __restrict__ in,
    const float* __restrict__ wt, const float* __restrict__ bias,
    float* __restrict__ out) {
  constexpr int HW = HOUT*WOUT;
  constexpr int PX = 256/COPB;
  constexpr int NBLK = (HW + PX - 1)/PX;
  const int cog = blockIdx.x / NBLK;
  const int tb  = blockIdx.x % NBLK;
  const int tid = threadIdx.x;
  const int cosub = tid / PX;
  const int co = cog*COPB + cosub;
  const int idx = tb*PX + (tid & (PX-1));
  __shared__ float wl[COPB*CIN*9];
  for (int i = tid; i < COPB*CIN*9; i += 256) wl[i] = wt[cog*COPB*CIN*9 + i];
  __syncthreads();
  if (idx >= HW) return;
  const float* wp0 = wl + cosub*CIN*9;
  const int oh = idx / WOUT;
  const int ow = idx - oh*WOUT;
  const int ih0 = oh*2 - 1, iw0 = ow*2 - 1;
  float s = bias[co];
  if (oh >= 1 && ow >= 1) {
    // interior: all 9 taps valid
    const float* ipb = in + ih0*WIN + iw0;
    #pragma unroll 4
    for (int ci = 0; ci < CIN; ++ci) {
      const float* ip = ipb + ci*HIN*WIN;
      const float* wp = wp0 + ci*9;
      #pragma unroll
      for (int kh = 0; kh < 3; ++kh)
        #pragma unroll
        for (int kw = 0; kw < 3; ++kw)
          s += ip[kh*WIN + kw] * wp[kh*3 + kw];
    }
  } else {
    for (int ci = 0; ci < CIN; ++ci) {
      const float* ip = in + ci*HIN*WIN;
      const float* wp = wp0 + ci*9;
      #pragma unroll
      for (int kh = 0; kh < 3; ++kh) {
        const int ih = ih0 + kh;
        if (ih < 0) continue;
        #pragma unroll
        for (int kw = 0; kw < 3; ++kw) {
          const int iw = iw0 + kw;
          if (iw < 0) continue;
          s += ip[ih*WIN + iw] * wp[kh*3 + kw];
        }
      }
    }
  }
  if (LRELU) s = s >= 0.f ? s : 0.2f*s;
  out[(size_t)co*HW + idx] = s;
}

// ---------------- instance norm (in place), one block per channel ----------------
template<int HW>
__global__ __launch_bounds__(256) void inorm_kernel(float* __restrict__ x,
    const float* __restrict__ gam, const float* __restrict__ bet) {
  __shared__ float sx[HW];
  __shared__ float red[256];
  const int co = blockIdx.x;
  float* ch = x + (size_t)co*HW;
  const int tid = threadIdx.x;
  float ls = 0.f;
  for (int i = tid; i < HW; i += 256) { float v = ch[i]; sx[i] = v; ls += v; }
  red[tid] = ls; __syncthreads();
  for (int s = 128; s > 0; s >>= 1) { if (tid < s) red[tid] += red[tid+s]; __syncthreads(); }
  const float mean = red[0] * (1.f/HW);
  __syncthreads();
  float lv = 0.f;
  for (int i = tid; i < HW; i += 256) { float d = sx[i]-mean; lv += d*d; }
  red[tid] = lv; __syncthreads();
  for (int s = 128; s > 0; s >>= 1) { if (tid < s) red[tid] += red[tid+s]; __syncthreads(); }
  const float sc = rsqrtf(red[0] * (1.f/HW) + 1e-5f) * gam[co];
  const float sh = bet[co];
  for (int i = tid; i < HW; i += 256) ch[i] = (sx[i]-mean)*sc + sh;
}

// ---------------- conv6: (128,8,8) . (3,128,8,8) + b -> pred[3] ----------------
__global__ void conv6_kernel(const float* __restrict__ in, const float* __restrict__ wt,
                             const float* __restrict__ bias, float* __restrict__ pred) {
  __shared__ float red[256];
  const int tid = threadIdx.x;
  for (int co = 0; co < 3; ++co) {
    float s = 0.f;
    for (int e = tid; e < 8192; e += 256) s += in[e] * wt[co*8192 + e];
    red[tid] = s;
    __syncthreads();
    for (int k = 128; k > 0; k >>= 1) {
      if (tid < k) red[tid] += red[tid + k];
      __syncthreads();
    }
    if (tid == 0) pred[co] = red[0] + bias[co];
    __syncthreads();
  }
}

// ---------------- final LUT blend ----------------
__global__ void final_lut_kernel(const float* __restrict__ l0, const float* __restrict__ l1,
                                 const float* __restrict__ l2, const float* __restrict__ pred,
                                 float* __restrict__ fl) {
  const int i = blockIdx.x*256 + threadIdx.x;
  if (i < 3*35937) fl[i] = pred[0]*l0[i] + pred[1]*l1[i] + pred[2]*l2[i];
}

// ---------------- trilinear apply: per-channel LUT staged in LDS (143.7 KB) ----------------
__global__ __launch_bounds__(1024) void trilinear_kernel(const float* __restrict__ img,
    const float* __restrict__ fl, float* __restrict__ out) {
  __shared__ float slut[35937];
  const int tid = threadIdx.x;
  const int p0 = blockIdx.x * 32400;     // 256 blocks * 32400 = 8,294,400 exactly
  const int p1 = p0 + 32400;
  for (int c = 0; c < 3; ++c) {
    for (int i = tid; i < 35937; i += 1024) slut[i] = fl[c*35937 + i];
    __syncthreads();
    for (int p = p0 + tid; p < p1; p += 1024) {
      const float r = img[p];
      const float g = img[NPX + p];
      const float b = img[2*NPX + p];
      const float xr = r*32.f, xg = g*32.f, xb = b*32.f;
      int ir = (int)floorf(xr); ir = ir < 0 ? 0 : (ir > 31 ? 31 : ir);
      int ig = (int)floorf(xg); ig = ig < 0 ? 0 : (ig > 31 ? 31 : ig);
      int ib = (int)floorf(xb); ib = ib < 0 ? 0 : (ib > 31 ? 31 : ib);
      const float fr = xr - (float)ir;
      const float fg = xg - (float)ig;
      const float fb = xb - (float)ib;
      const int base = (ib*33 + ig)*33 + ir;
      const float v000 = slut[base],      v001 = slut[base+1];
      const float v010 = slut[base+33],   v011 = slut[base+34];
      const float v100 = slut[base+1089], v101 = slut[base+1090];
      const float v110 = slut[base+1122], v111 = slut[base+1123];
      const float wr0 = 1.f - fr;
      const float wg0 = 1.f - fg;
      const float wb0 = 1.f - fb;
      const float lo = wg0*(v000*wr0 + v001*fr) + fg*(v010*wr0 + v011*fr);
      const float hi = wg0*(v100*wr0 + v101*fr) + fg*(v110*wr0 + v111*fr);
      out[c*NPX + p] = wb0*lo + fb*hi;
    }
    __syncthreads();
  }
}

extern "C" void kernel_launch(void* const* d_in, const int* in_sizes, int n_in,
                              void* d_out, int out_size, void* d_ws, size_t ws_size,
                              hipStream_t stream) {
  const float* img  = (const float*)d_in[0];
  const float* lut0 = (const float*)d_in[1];
  const float* lut1 = (const float*)d_in[2];
  const float* lut2 = (const float*)d_in[3];
  const float* w1 = (const float*)d_in[4];  const float* b1  = (const float*)d_in[5];
  const float* g1 = (const float*)d_in[6];  const float* be1 = (const float*)d_in[7];
  const float* w2 = (const float*)d_in[8];  const float* b2  = (const float*)d_in[9];
  const float* g2 = (const float*)d_in[10]; const float* be2 = (const float*)d_in[11];
  const float* w3 = (const float*)d_in[12]; const float* b3  = (const float*)d_in[13];
  const float* g3 = (const float*)d_in[14]; const float* be3 = (const float*)d_in[15];
  const float* w4 = (const float*)d_in[16]; const float* b4  = (const float*)d_in[17];
  const float* g4 = (const float*)d_in[18]; const float* be4 = (const float*)d_in[19];
  const float* w5 = (const float*)d_in[20]; const float* b5  = (const float*)d_in[21];
  const float* w6 = (const float*)d_in[22]; const float* b6  = (const float*)d_in[23];

  float* ws = (float*)d_ws;
  float* tmp  = ws;                  // 3*2160*256 = 1,658,880 (dead after resize_h)
  float* r256 = ws + 1658880;        // 3*256*256 = 196,608
  float* c1   = ws;                  // 16*128*128 = 262,144 (tmp dead by now)
  float* c2   = ws + 262144;         // 32*64*64  = 131,072
  float* c3   = ws + 393216;         // 64*32*32  =  65,536
  float* c4   = ws + 458752;         // 128*16*16 =  32,768
  float* c5   = ws + 491520;         // 128*8*8   =   8,192
  float* pred = ws + 499712;         // 3 (pad 4)
  float* flut = ws + 499716;         // 3*35937 = 107,811

  resize_w_kernel<<<3*2160, 256, 0, stream>>>(img, tmp);
  resize_h_kernel<<<3*256, 256, 0, stream>>>(tmp, r256);

  conv_direct<  3,256,256,128,128,1,true><<< 16*64,256,0,stream>>>(r256, w1, b1, c1);
  inorm_kernel<16384><<< 16,256,0,stream>>>(c1, g1, be1);
  conv_direct< 16,128,128, 64, 64,1,true><<< 32*16,256,0,stream>>>(c1, w2, b2, c2);
  inorm_kernel< 4096><<< 32,256,0,stream>>>(c2, g2, be2);
  conv_direct< 32, 64, 64, 32, 32,1,true><<< 64* 4,256,0,stream>>>(c2, w3, b3, c3);
  inorm_kernel< 1024><<< 64,256,0,stream>>>(c3, g3, be3);
  conv_direct< 64, 32, 32, 16, 16,1,true><<<128* 1,256,0,stream>>>(c3, w4, b4, c4);
  inorm_kernel<  256><<<128,256,0,stream>>>(c4, g4, be4);
  conv_direct<128, 16, 16,  8,  8,4,true><<< 32* 1,256,0,stream>>>(c4, w5, b5, c5);

  conv6_kernel<<<1, 256, 0, stream>>>(c5, w6, b6, pred);
  final_lut_kernel<<<422, 256, 0, stream>>>(lut0, lut1, lut2, pred, flut);
  trilinear_kernel<<<256, 1024, 0, stream>>>(img, flut, (float*)d_out);
}

// Round 3
// 274.556 us; speedup vs baseline: 1.7527x; 1.4318x over previous
//
#include <hip/hip_runtime.h>

#define NPX (2160*3840)

// ---------------- resize along W: (3,2160,3840) -> (3,2160,256) ----------------
__global__ void resize_w_kernel(const float* __restrict__ img, float* __restrict__ tmp) {
  __shared__ __align__(16) float row[3840];
  const int bh = blockIdx.x;            // c*2160 + h
  const float* src = img + (size_t)bh * 3840;
  const int tid = threadIdx.x;          // 256
  const float4* s4 = (const float4*)src;
  float4* r4 = (float4*)row;
  for (int i = tid; i < 960; i += 256) r4[i] = s4[i];
  __syncthreads();
  const int i = tid;
  const int center = 15*i + 7;
  int lo = center - 14; if (lo < 0) lo = 0;
  int hi = center + 14; if (hi > 3839) hi = 3839;
  float acc = 0.f, wsum = 0.f;
  for (int j = lo; j <= hi; ++j) {
    int d = center - j; d = d < 0 ? -d : d;
    float w = (float)(15 - d);
    acc += w * row[j];
    wsum += w;
  }
  tmp[bh*256 + i] = acc / wsum;
}

// ---------------- resize along H: (3,2160,256) -> (3,256,256) ----------------
__global__ void resize_h_kernel(const float* __restrict__ tmp, float* __restrict__ dst) {
  const int c = blockIdx.x >> 8;
  const int oh = blockIdx.x & 255;
  const int ow = threadIdx.x;           // 256
  const float sf = ((float)oh + 0.5f) * 8.4375f - 0.5f;
  int lo = (int)ceilf(sf - 8.4375f); if (lo < 0) lo = 0;
  int hi = (int)floorf(sf + 8.4375f); if (hi > 2159) hi = 2159;
  float acc = 0.f, wsum = 0.f;
  for (int j = lo; j <= hi; ++j) {
    float w = 1.f - fabsf(sf - (float)j) * (16.f/135.f);
    if (w > 0.f) {
      acc += w * tmp[(c*2160 + j)*256 + ow];
      wsum += w;
    }
  }
  dst[blockIdx.x*256 + ow] = acc / wsum;
}

// ---------------- direct conv3x3(stride2,pad1) + bias + lrelu (shallow CIN) ----------------
template<int CIN,int HIN,int WIN,int HOUT,int WOUT,bool LRELU>
__global__ __launch_bounds__(256) void conv_direct(const float* __restrict__ in,
    const float* __restrict__ wt, const float* __restrict__ bias,
    float* __restrict__ out) {
  constexpr int HW = HOUT*WOUT;
  constexpr int NBLK = (HW + 255)/256;
  const int co = blockIdx.x / NBLK;
  const int tb  = blockIdx.x % NBLK;
  const int tid = threadIdx.x;
  const int idx = tb*256 + tid;
  __shared__ float wl[CIN*9];
  for (int i = tid; i < CIN*9; i += 256) wl[i] = wt[co*CIN*9 + i];
  __syncthreads();
  if (idx >= HW) return;
  const int oh = idx / WOUT;
  const int ow = idx - oh*WOUT;
  const int ih0 = oh*2 - 1, iw0 = ow*2 - 1;
  float s = bias[co];
  if (oh >= 1 && ow >= 1) {
    const float* ipb = in + ih0*WIN + iw0;
    #pragma unroll
    for (int ci = 0; ci < CIN; ++ci) {
      const float* ip = ipb + ci*HIN*WIN;
      const float* wp = wl + ci*9;
      #pragma unroll
      for (int kh = 0; kh < 3; ++kh)
        #pragma unroll
        for (int kw = 0; kw < 3; ++kw)
          s += ip[kh*WIN + kw] * wp[kh*3 + kw];
    }
  } else {
    #pragma unroll
    for (int ci = 0; ci < CIN; ++ci) {
      const float* ip = in + ci*HIN*WIN;
      const float* wp = wl + ci*9;
      #pragma unroll
      for (int kh = 0; kh < 3; ++kh) {
        const int ih = ih0 + kh;
        if (ih < 0) continue;
        #pragma unroll
        for (int kw = 0; kw < 3; ++kw) {
          const int iw = iw0 + kw;
          if (iw < 0) continue;
          s += ip[ih*WIN + iw] * wp[kh*3 + kw];
        }
      }
    }
  }
  if (LRELU) s = s >= 0.f ? s : 0.2f*s;
  out[(size_t)co*HW + idx] = s;
}

// ---------------- conv4: 64x32x32 -> 128x16x16, LDS-staged input ----------------
__global__ __launch_bounds__(256) void conv4_lds(const float* __restrict__ in,
    const float* __restrict__ wt, const float* __restrict__ bias,
    float* __restrict__ out) {
  __shared__ float sin4[16*1024];    // [ci][ih][iw], 64 KB per 16-ci chunk
  __shared__ float wl[576];
  const int co = blockIdx.x;         // 128
  const int tid = threadIdx.x;
  for (int i = tid; i < 576; i += 256) wl[i] = wt[co*576 + i];
  const int oh = tid >> 4, ow = tid & 15;
  const int ih0 = 2*oh - 1, iw0 = 2*ow - 1;
  float acc = bias[co];
  const float4* g4 = (const float4*)in;
  float4* s4 = (float4*)sin4;
  for (int c = 0; c < 4; ++c) {
    __syncthreads();
    for (int i = tid; i < 4096; i += 256) s4[i] = g4[c*4096 + i];
    __syncthreads();
    const float* wp0 = wl + c*144;
    #pragma unroll 4
    for (int ci = 0; ci < 16; ++ci) {
      const float* sp = sin4 + ci*1024;
      const float* wp = wp0 + ci*9;
      #pragma unroll
      for (int kh = 0; kh < 3; ++kh) {
        const int ih = ih0 + kh; if (ih < 0) continue;
        const float* rp = sp + ih*32;
        #pragma unroll
        for (int kw = 0; kw < 3; ++kw) {
          const int iw = iw0 + kw; if (iw < 0) continue;
          acc += rp[iw] * wp[kh*3 + kw];
        }
      }
    }
  }
  acc = acc >= 0.f ? acc : 0.2f*acc;
  out[co*256 + tid] = acc;
}

// ---------------- conv5 fused with conv6 partial dots ----------------
// in: c4 (128x16x16). Each block: 4 output channels x 64 px. Writes 3 partial
// sums per block: partial[cog*3+j] = sum acc * w6[j,co,px].
__global__ __launch_bounds__(256) void conv5_fused(const float* __restrict__ in,
    const float* __restrict__ wt, const float* __restrict__ bias,
    const float* __restrict__ w6, float* __restrict__ partial) {
  __shared__ float sin5[32*288];     // [ci][ih][iw] row-stride 18 (bank spread)
  __shared__ float wl[4*128*9];
  __shared__ float red[256];
  const int cog = blockIdx.x;        // 32
  const int tid = threadIdx.x;
  for (int i = tid; i < 4608; i += 256) wl[i] = wt[cog*4608 + i];
  const int cosub = tid >> 6;
  const int co = cog*4 + cosub;
  const int px = tid & 63;
  const int oh = px >> 3, ow = px & 7;
  const int ih0 = 2*oh - 1, iw0 = 2*ow - 1;
  float acc = bias[co];
  for (int c = 0; c < 4; ++c) {
    __syncthreads();
    for (int i = tid; i < 8192; i += 256) {
      const int ci = i >> 8, rem = i & 255;
      sin5[ci*288 + (rem>>4)*18 + (rem&15)] = in[c*8192 + i];
    }
    __syncthreads();
    const float* wlp = wl + cosub*1152 + c*288;
    #pragma unroll 8
    for (int ci = 0; ci < 32; ++ci) {
      const float* sp = sin5 + ci*288;
      const float* wp = wlp + ci*9;
      #pragma unroll
      for (int kh = 0; kh < 3; ++kh) {
        const int ih = ih0 + kh; if (ih < 0) continue;
        const float* rp = sp + ih*18;
        #pragma unroll
        for (int kw = 0; kw < 3; ++kw) {
          const int iw = iw0 + kw; if (iw < 0) continue;
          acc += rp[iw] * wp[kh*3 + kw];
        }
      }
    }
  }
  acc = acc >= 0.f ? acc : 0.2f*acc;
  const int wi = co*64 + px;
  #pragma unroll
  for (int j = 0; j < 3; ++j) {
    red[tid] = acc * w6[j*8192 + wi];
    __syncthreads();
    for (int s = 128; s > 0; s >>= 1) { if (tid < s) red[tid] += red[tid+s]; __syncthreads(); }
    if (tid == 0) partial[cog*3 + j] = red[0];
    __syncthreads();
  }
}

// ---------------- instance norm (in place), one block per channel ----------------
template<int HW>
__global__ __launch_bounds__(256) void inorm_kernel(float* __restrict__ x,
    const float* __restrict__ gam, const float* __restrict__ bet) {
  __shared__ float sx[HW];
  __shared__ float red[256];
  const int co = blockIdx.x;
  float* ch = x + (size_t)co*HW;
  const int tid = threadIdx.x;
  float ls = 0.f;
  for (int i = tid; i < HW; i += 256) { float v = ch[i]; sx[i] = v; ls += v; }
  red[tid] = ls; __syncthreads();
  for (int s = 128; s > 0; s >>= 1) { if (tid < s) red[tid] += red[tid+s]; __syncthreads(); }
  const float mean = red[0] * (1.f/HW);
  __syncthreads();
  float lv = 0.f;
  for (int i = tid; i < HW; i += 256) { float d = sx[i]-mean; lv += d*d; }
  red[tid] = lv; __syncthreads();
  for (int s = 128; s > 0; s >>= 1) { if (tid < s) red[tid] += red[tid+s]; __syncthreads(); }
  const float sc = rsqrtf(red[0] * (1.f/HW) + 1e-5f) * gam[co];
  const float sh = bet[co];
  for (int i = tid; i < HW; i += 256) ch[i] = (sx[i]-mean)*sc + sh;
}

// ---------------- final LUT blend (sums conv6 partials per block) ----------------
__global__ void final_lut_kernel(const float* __restrict__ l0, const float* __restrict__ l1,
                                 const float* __restrict__ l2, const float* __restrict__ partial,
                                 const float* __restrict__ b6, float* __restrict__ fl) {
  __shared__ float sp[3];
  const int tid = threadIdx.x;
  if (tid < 3) {
    float s = b6[tid];
    #pragma unroll
    for (int k = 0; k < 32; ++k) s += partial[k*3 + tid];
    sp[tid] = s;
  }
  __syncthreads();
  const int i = blockIdx.x*256 + tid;
  if (i < 3*35937) fl[i] = sp[0]*l0[i] + sp[1]*l1[i] + sp[2]*l2[i];
}

// ---------------- trilinear apply: per-channel LUT staged in LDS ----------------
__global__ __launch_bounds__(1024) void trilinear_kernel(const float* __restrict__ img,
    const float* __restrict__ fl, float* __restrict__ out) {
  __shared__ float slut[35937];
  const int tid = threadIdx.x;
  const int p0 = blockIdx.x * 32400;     // 256 blocks * 32400 = 8,294,400 exactly
  const int p1 = p0 + 32400;
  for (int c = 0; c < 3; ++c) {
    __syncthreads();
    for (int i = tid; i < 35937; i += 1024) slut[i] = fl[c*35937 + i];
    __syncthreads();
    for (int p = p0 + tid; p < p1; p += 1024) {
      const float r = img[p];
      const float g = img[NPX + p];
      const float b = img[2*NPX + p];
      const float xr = r*32.f, xg = g*32.f, xb = b*32.f;
      int ir = (int)floorf(xr); ir = ir < 0 ? 0 : (ir > 31 ? 31 : ir);
      int ig = (int)floorf(xg); ig = ig < 0 ? 0 : (ig > 31 ? 31 : ig);
      int ib = (int)floorf(xb); ib = ib < 0 ? 0 : (ib > 31 ? 31 : ib);
      const float fr = xr - (float)ir;
      const float fg = xg - (float)ig;
      const float fb = xb - (float)ib;
      const int base = (ib*33 + ig)*33 + ir;
      const float v000 = slut[base],      v001 = slut[base+1];
      const float v010 = slut[base+33],   v011 = slut[base+34];
      const float v100 = slut[base+1089], v101 = slut[base+1090];
      const float v110 = slut[base+1122], v111 = slut[base+1123];
      const float wr0 = 1.f - fr;
      const float wg0 = 1.f - fg;
      const float wb0 = 1.f - fb;
      const float lo = wg0*(v000*wr0 + v001*fr) + fg*(v010*wr0 + v011*fr);
      const float hi = wg0*(v100*wr0 + v101*fr) + fg*(v110*wr0 + v111*fr);
      out[c*NPX + p] = wb0*lo + fb*hi;
    }
  }
}

extern "C" void kernel_launch(void* const* d_in, const int* in_sizes, int n_in,
                              void* d_out, int out_size, void* d_ws, size_t ws_size,
                              hipStream_t stream) {
  const float* img  = (const float*)d_in[0];
  const float* lut0 = (const float*)d_in[1];
  const float* lut1 = (const float*)d_in[2];
  const float* lut2 = (const float*)d_in[3];
  const float* w1 = (const float*)d_in[4];  const float* b1  = (const float*)d_in[5];
  const float* g1 = (const float*)d_in[6];  const float* be1 = (const float*)d_in[7];
  const float* w2 = (const float*)d_in[8];  const float* b2  = (const float*)d_in[9];
  const float* g2 = (const float*)d_in[10]; const float* be2 = (const float*)d_in[11];
  const float* w3 = (const float*)d_in[12]; const float* b3  = (const float*)d_in[13];
  const float* g3 = (const float*)d_in[14]; const float* be3 = (const float*)d_in[15];
  const float* w4 = (const float*)d_in[16]; const float* b4  = (const float*)d_in[17];
  const float* g4 = (const float*)d_in[18]; const float* be4 = (const float*)d_in[19];
  const float* w5 = (const float*)d_in[20]; const float* b5  = (const float*)d_in[21];
  const float* w6 = (const float*)d_in[22]; const float* b6  = (const float*)d_in[23];

  float* ws = (float*)d_ws;
  float* tmp  = ws;                  // 3*2160*256 = 1,658,880 (dead after resize_h)
  float* r256 = ws + 1658880;        // 3*256*256 = 196,608
  float* c1   = ws;                  // 16*128*128 = 262,144 (tmp dead by now)
  float* c2   = ws + 262144;         // 32*64*64  = 131,072
  float* c3   = ws + 393216;         // 64*32*32  =  65,536
  float* c4   = ws + 458752;         // 128*16*16 =  32,768
  float* part = ws + 491520;         // 96 (pad 128)
  float* flut = ws + 491648;         // 3*35937 = 107,811

  resize_w_kernel<<<3*2160, 256, 0, stream>>>(img, tmp);
  resize_h_kernel<<<3*256, 256, 0, stream>>>(tmp, r256);

  conv_direct<  3,256,256,128,128,true><<< 16*64,256,0,stream>>>(r256, w1, b1, c1);
  inorm_kernel<16384><<< 16,256,0,stream>>>(c1, g1, be1);
  conv_direct< 16,128,128, 64, 64,true><<< 32*16,256,0,stream>>>(c1, w2, b2, c2);
  inorm_kernel< 4096><<< 32,256,0,stream>>>(c2, g2, be2);
  conv_direct< 32, 64, 64, 32, 32,true><<< 64* 4,256,0,stream>>>(c2, w3, b3, c3);
  inorm_kernel< 1024><<< 64,256,0,stream>>>(c3, g3, be3);
  conv4_lds<<<128, 256, 0, stream>>>(c3, w4, b4, c4);
  inorm_kernel<  256><<<128,256,0,stream>>>(c4, g4, be4);
  conv5_fused<<<32, 256, 0, stream>>>(c4, w5, b5, w6, part);

  final_lut_kernel<<<422, 256, 0, stream>>>(lut0, lut1, lut2, part, b6, flut);
  trilinear_kernel<<<256, 1024, 0, stream>>>(img, flut, (float*)d_out);
}

// Round 4
// 218.454 us; speedup vs baseline: 2.2028x; 1.2568x over previous
//
#include <hip/hip_runtime.h>

#define NPX (2160*3840)
#define EPS 1e-5f

// ---------------- resize along W: (3,2160,3840) -> (3,2160,256) ----------------
__global__ void resize_w_kernel(const float* __restrict__ img, float* __restrict__ tmp) {
  __shared__ __align__(16) float row[3840];
  const int bh = blockIdx.x;            // c*2160 + h
  const float* src = img + (size_t)bh * 3840;
  const int tid = threadIdx.x;          // 256
  const float4* s4 = (const float4*)src;
  float4* r4 = (float4*)row;
  for (int i = tid; i < 960; i += 256) r4[i] = s4[i];
  __syncthreads();
  const int i = tid;
  const int center = 15*i + 7;
  int lo = center - 14; if (lo < 0) lo = 0;
  int hi = center + 14; if (hi > 3839) hi = 3839;
  float acc = 0.f, wsum = 0.f;
  for (int j = lo; j <= hi; ++j) {
    int d = center - j; d = d < 0 ? -d : d;
    float w = (float)(15 - d);
    acc += w * row[j];
    wsum += w;
  }
  tmp[bh*256 + i] = acc / wsum;
}

// ---------------- resize along H: (3,2160,256) -> (3,256,256) ----------------
__global__ void resize_h_kernel(const float* __restrict__ tmp, float* __restrict__ dst) {
  const int c = blockIdx.x >> 8;
  const int oh = blockIdx.x & 255;
  const int ow = threadIdx.x;           // 256
  const float sf = ((float)oh + 0.5f) * 8.4375f - 0.5f;
  int lo = (int)ceilf(sf - 8.4375f); if (lo < 0) lo = 0;
  int hi = (int)floorf(sf + 8.4375f); if (hi > 2159) hi = 2159;
  float acc = 0.f, wsum = 0.f;
  for (int j = lo; j <= hi; ++j) {
    float w = 1.f - fabsf(sf - (float)j) * (16.f/135.f);
    if (w > 0.f) {
      acc += w * tmp[(c*2160 + j)*256 + ow];
      wsum += w;
    }
  }
  dst[blockIdx.x*256 + ow] = acc / wsum;
}

// ---------------- fused conv3x3(s2,p1) + input-norm-on-stage + lrelu + stats ----------------
// Tile = 16x16 outputs per block (256 threads, 1 px each). Input region staged in LDS,
// zero-padded (no border branches). If NPIN>0: input is normalized on staging using
// partials from the producer layer. MODE: 1 = emit (sum,sumsq) partial per (co,tile);
// 2 = whole-channel block (NT==1): emit A/B for this layer directly (pout[co*2],pout[co*2+1]).
template<int CIN,int CICHUNK,int HIN,int WIN,int HOUT,int WOUT,int NPIN,int MODE>
__global__ __launch_bounds__(256) void conv_fused(
    const float* __restrict__ in, const float* __restrict__ wt, const float* __restrict__ bias,
    const float* __restrict__ pin, const float* __restrict__ gin, const float* __restrict__ bin,
    float* __restrict__ out, float* __restrict__ pout,
    const float* __restrict__ gself, const float* __restrict__ bself) {
  constexpr int NTW = WOUT/16;
  constexpr int NT  = (HOUT/16)*NTW;
  constexpr int NCHUNK = CIN/CICHUNK;
  constexpr int SLOTS = CICHUNK*33*9;          // float4 slots per chunk
  constexpr float PHW_INV = 1.f/(float)(HIN*WIN); // producer spatial size

  __shared__ float sx[CICHUNK*33*36];
  __shared__ float wl[CIN*9];
  __shared__ float sA[CIN], sB[CIN];
  __shared__ float2 red2[256];

  const int co = blockIdx.x / NT;
  const int t  = blockIdx.x % NT;
  const int oh0 = (t / NTW)*16, ow0 = (t % NTW)*16;
  const int tid = threadIdx.x;

  for (int i = tid; i < CIN*9; i += 256) wl[i] = wt[co*CIN*9 + i];
  if (NPIN > 0) {
    if (tid < CIN) {
      const float2* p2 = (const float2*)pin;
      float s = 0.f, q = 0.f;
      #pragma unroll 4
      for (int k = 0; k < NPIN; ++k) { float2 p = p2[tid*NPIN + k]; s += p.x; q += p.y; }
      const float m = s * PHW_INV;
      float var = q * PHW_INV - m*m; var = fmaxf(var, 0.f);
      const float A = gin[tid] * rsqrtf(var + EPS);
      sA[tid] = A; sB[tid] = bin[tid] - m*A;
    }
  }
  __syncthreads();

  const int ohl = tid >> 4, owl = tid & 15;
  float acc = bias[co];

  for (int cc = 0; cc < NCHUNK; ++cc) {
    if (cc) __syncthreads();
    const int cb = cc*CICHUNK;
    for (int i = tid; i < SLOTS; i += 256) {
      const int ci_l = i / 297;
      const int rem  = i - ci_l*297;
      const int r = rem / 9, q = rem - r*9;
      const int grow = 2*oh0 - 1 + r;
      const int ga   = 2*ow0 - 4 + 4*q;
      float4 v = make_float4(0.f,0.f,0.f,0.f);
      if (grow >= 0 && grow < HIN && ga >= 0) {
        v = *(const float4*)(in + ((size_t)(cb+ci_l)*HIN + grow)*WIN + ga);
        if (NPIN > 0) {
          const float A = sA[cb+ci_l], B = sB[cb+ci_l];
          v.x = fmaf(A, v.x, B); v.y = fmaf(A, v.y, B);
          v.z = fmaf(A, v.z, B); v.w = fmaf(A, v.w, B);
        }
      }
      *(float4*)&sx[(ci_l*33 + r)*36 + q*4] = v;
    }
    __syncthreads();
    #pragma unroll 4
    for (int ci_l = 0; ci_l < CICHUNK; ++ci_l) {
      const float* sp = sx + ci_l*1188;
      const float* wp = wl + (cb+ci_l)*9;
      #pragma unroll
      for (int kh = 0; kh < 3; ++kh) {
        const float* rp = sp + (2*ohl + kh)*36 + 3 + 2*owl;
        acc = fmaf(rp[0], wp[kh*3+0], acc);
        acc = fmaf(rp[1], wp[kh*3+1], acc);
        acc = fmaf(rp[2], wp[kh*3+2], acc);
      }
    }
  }

  acc = acc >= 0.f ? acc : 0.2f*acc;
  out[(size_t)co*HOUT*WOUT + (oh0+ohl)*WOUT + ow0 + owl] = acc;

  // stats
  red2[tid] = make_float2(acc, acc*acc);
  __syncthreads();
  for (int s = 128; s > 0; s >>= 1) {
    if (tid < s) { red2[tid].x += red2[tid+s].x; red2[tid].y += red2[tid+s].y; }
    __syncthreads();
  }
  if (tid == 0) {
    if (MODE == 1) {
      ((float2*)pout)[co*NT + t] = red2[0];
    } else { // MODE 2: whole channel in block
      const float m = red2[0].x / (float)(HOUT*WOUT);
      float var = red2[0].y / (float)(HOUT*WOUT) - m*m; var = fmaxf(var, 0.f);
      const float A = gself[co] * rsqrtf(var + EPS);
      pout[co*2]   = A;
      pout[co*2+1] = bself[co] - m*A;
    }
  }
}

// ---------------- conv5 (128ci,16x16 -> 1co,8x8) + lrelu + w6 dot partials ----------------
// grid 128 (one co each), 256 thr = 64 px x 4 ci-groups. Input normalized via ab4.
__global__ __launch_bounds__(256) void conv5_fused(const float* __restrict__ in,
    const float* __restrict__ wt, const float* __restrict__ bias,
    const float* __restrict__ ab4, const float* __restrict__ w6,
    float* __restrict__ part) {
  __shared__ float sx[32*17*20];
  __shared__ float wl[128*9];
  __shared__ float sA[128], sB[128];
  __shared__ float red[256];
  const int co = blockIdx.x;
  const int tid = threadIdx.x;
  for (int i = tid; i < 1152; i += 256) wl[i] = wt[co*1152 + i];
  if (tid < 128) { sA[tid] = ab4[tid*2]; sB[tid] = ab4[tid*2+1]; }
  __syncthreads();

  const int px = tid & 63, q = tid >> 6;
  const int ohl = px >> 3, owl = px & 7;
  float acc = 0.f;
  for (int cc = 0; cc < 4; ++cc) {
    if (cc) __syncthreads();
    const int cb = cc*32;
    for (int i = tid; i < 32*17*5; i += 256) {   // 2720 float4 slots
      const int ci_l = i / 85;
      const int rem  = i - ci_l*85;
      const int r = rem / 5, qq = rem - r*5;
      const int grow = r - 1;
      const int ga   = 4*qq - 4;
      float4 v = make_float4(0.f,0.f,0.f,0.f);
      if (grow >= 0 && grow < 16 && ga >= 0) {
        v = *(const float4*)(in + ((size_t)(cb+ci_l)*16 + grow)*16 + ga);
        const float A = sA[cb+ci_l], B = sB[cb+ci_l];
        v.x = fmaf(A, v.x, B); v.y = fmaf(A, v.y, B);
        v.z = fmaf(A, v.z, B); v.w = fmaf(A, v.w, B);
      }
      *(float4*)&sx[(ci_l*17 + r)*20 + qq*4] = v;
    }
    __syncthreads();
    #pragma unroll 2
    for (int k = 0; k < 8; ++k) {
      const int ci_l = q*8 + k;
      const float* sp = sx + ci_l*340;
      const float* wp = wl + (cb+ci_l)*9;
      #pragma unroll
      for (int kh = 0; kh < 3; ++kh) {
        const float* rp = sp + (2*ohl + kh)*20 + 3 + 2*owl;
        acc = fmaf(rp[0], wp[kh*3+0], acc);
        acc = fmaf(rp[1], wp[kh*3+1], acc);
        acc = fmaf(rp[2], wp[kh*3+2], acc);
      }
    }
  }
  red[tid] = acc;
  __syncthreads();
  if (tid < 64) {
    float a = red[tid] + red[tid+64] + red[tid+128] + red[tid+192] + bias[co];
    a = a >= 0.f ? a : 0.2f*a;
    #pragma unroll
    for (int j = 0; j < 3; ++j) {
      float v = a * w6[(j*128 + co)*64 + tid];
      #pragma unroll
      for (int off = 32; off > 0; off >>= 1) v += __shfl_down(v, off);
      if (tid == 0) part[co*3 + j] = v;
    }
  }
}

// ---------------- trilinear: pred-sum + blend-on-stage (bf16 pairs) + apply ----------------
__global__ __launch_bounds__(1024) void trilinear_kernel(const float* __restrict__ img,
    const float* __restrict__ l0, const float* __restrict__ l1, const float* __restrict__ l2,
    const float* __restrict__ part, const float* __restrict__ b6, float* __restrict__ out) {
  __shared__ unsigned slut[35936];
  __shared__ float spred[3];
  const int tid = threadIdx.x;
  if (tid < 3) {
    float s = b6[tid];
    #pragma unroll 16
    for (int k = 0; k < 128; ++k) s += part[k*3 + tid];
    spred[tid] = s;
  }
  const int p0 = blockIdx.x * 32400;     // 256 blocks * 32400 = 8,294,400 exactly
  const int p1 = p0 + 32400;
  for (int c = 0; c < 3; ++c) {
    __syncthreads();
    const float pr0 = spred[0], pr1 = spred[1], pr2 = spred[2];
    const int b = c*35937;
    for (int i = tid; i < 35936; i += 1024) {
      const float v0 = pr0*l0[b+i]   + pr1*l1[b+i]   + pr2*l2[b+i];
      const float v1 = pr0*l0[b+i+1] + pr1*l1[b+i+1] + pr2*l2[b+i+1];
      unsigned u0 = __float_as_uint(v0); u0 = (u0 + 0x7fffu + ((u0>>16)&1u)) >> 16;
      unsigned u1 = __float_as_uint(v1); u1 = (u1 + 0x7fffu + ((u1>>16)&1u)) >> 16;
      slut[i] = u0 | (u1 << 16);
    }
    __syncthreads();
    for (int p = p0 + 2*tid; p < p1; p += 2048) {
      const float2 rr = *(const float2*)(img + p);
      const float2 gg = *(const float2*)(img + NPX + p);
      const float2 bb = *(const float2*)(img + 2*NPX + p);
      float2 res;
      #pragma unroll
      for (int k = 0; k < 2; ++k) {
        const float r = k ? rr.y : rr.x;
        const float g = k ? gg.y : gg.x;
        const float bch = k ? bb.y : bb.x;
        const float xr = r*32.f, xg = g*32.f, xb = bch*32.f;
        int ir = (int)xr; ir = ir > 31 ? 31 : ir;
        int ig = (int)xg; ig = ig > 31 ? 31 : ig;
        int ib = (int)xb; ib = ib > 31 ? 31 : ib;
        const float fr = xr - (float)ir;
        const float fg = xg - (float)ig;
        const float fb = xb - (float)ib;
        const int base = (ib*33 + ig)*33 + ir;
        const unsigned p00 = slut[base],      p01 = slut[base+33];
        const unsigned p10 = slut[base+1089], p11 = slut[base+1122];
        const float v000 = __uint_as_float(p00 << 16), v001 = __uint_as_float(p00 & 0xffff0000u);
        const float v010 = __uint_as_float(p01 << 16), v011 = __uint_as_float(p01 & 0xffff0000u);
        const float v100 = __uint_as_float(p10 << 16), v101 = __uint_as_float(p10 & 0xffff0000u);
        const float v110 = __uint_as_float(p11 << 16), v111 = __uint_as_float(p11 & 0xffff0000u);
        const float a0 = fmaf(fr, v001 - v000, v000);
        const float a1 = fmaf(fr, v011 - v010, v010);
        const float a2 = fmaf(fr, v101 - v100, v100);
        const float a3 = fmaf(fr, v111 - v110, v110);
        const float lo = fmaf(fg, a1 - a0, a0);
        const float hi = fmaf(fg, a3 - a2, a2);
        const float vv = fmaf(fb, hi - lo, lo);
        if (k) res.y = vv; else res.x = vv;
      }
      *(float2*)(out + (size_t)c*NPX + p) = res;
    }
  }
}

extern "C" void kernel_launch(void* const* d_in, const int* in_sizes, int n_in,
                              void* d_out, int out_size, void* d_ws, size_t ws_size,
                              hipStream_t stream) {
  const float* img  = (const float*)d_in[0];
  const float* lut0 = (const float*)d_in[1];
  const float* lut1 = (const float*)d_in[2];
  const float* lut2 = (const float*)d_in[3];
  const float* w1 = (const float*)d_in[4];  const float* b1  = (const float*)d_in[5];
  const float* g1 = (const float*)d_in[6];  const float* be1 = (const float*)d_in[7];
  const float* w2 = (const float*)d_in[8];  const float* b2  = (const float*)d_in[9];
  const float* g2 = (const float*)d_in[10]; const float* be2 = (const float*)d_in[11];
  const float* w3 = (const float*)d_in[12]; const float* b3  = (const float*)d_in[13];
  const float* g3 = (const float*)d_in[14]; const float* be3 = (const float*)d_in[15];
  const float* w4 = (const float*)d_in[16]; const float* b4  = (const float*)d_in[17];
  const float* g4 = (const float*)d_in[18]; const float* be4 = (const float*)d_in[19];
  const float* w5 = (const float*)d_in[20]; const float* b5  = (const float*)d_in[21];
  const float* w6 = (const float*)d_in[22]; const float* b6  = (const float*)d_in[23];

  float* ws = (float*)d_ws;
  float* tmp   = ws;                 // 3*2160*256 = 1,658,880 (dead after resize_h)
  float* r256  = ws + 1658880;       // 3*256*256 = 196,608
  float* c1    = ws;                 // 16*128*128 = 262,144 (tmp dead)
  float* c2    = ws + 262144;        // 32*64*64  = 131,072
  float* c3    = ws + 393216;        // 64*32*32  =  65,536
  float* c4    = ws + 458752;        // 128*16*16 =  32,768
  float* part1 = ws + 491520;        // 16*64*2  = 2048
  float* part2 = ws + 493568;        // 32*16*2  = 1024
  float* part3 = ws + 494592;        // 64*4*2   = 512
  float* ab4   = ws + 495104;        // 128*2    = 256
  float* part6 = ws + 495360;        // 128*3    = 384

  resize_w_kernel<<<3*2160, 256, 0, stream>>>(img, tmp);
  resize_h_kernel<<<3*256, 256, 0, stream>>>(tmp, r256);

  conv_fused< 3, 3,256,256,128,128, 0,1><<<16*64, 256, 0, stream>>>(
      r256, w1, b1, nullptr, nullptr, nullptr, c1, part1, nullptr, nullptr);
  conv_fused<16,16,128,128, 64, 64,64,1><<<32*16, 256, 0, stream>>>(
      c1, w2, b2, part1, g1, be1, c2, part2, nullptr, nullptr);
  conv_fused<32,32, 64, 64, 32, 32,16,1><<<64*4, 256, 0, stream>>>(
      c2, w3, b3, part2, g2, be2, c3, part3, nullptr, nullptr);
  conv_fused<64,32, 32, 32, 16, 16, 4,2><<<128, 256, 0, stream>>>(
      c3, w4, b4, part3, g3, be3, c4, ab4, g4, be4);
  conv5_fused<<<128, 256, 0, stream>>>(c4, w5, b5, ab4, w6, part6);

  trilinear_kernel<<<256, 1024, 0, stream>>>(img, lut0, lut1, lut2, part6, b6, (float*)d_out);
}

// Round 6
// 198.760 us; speedup vs baseline: 2.4211x; 1.0991x over previous
//
#include <hip/hip_runtime.h>

#define NPX (2160*3840)
#define EPS 1e-5f

typedef float __attribute__((ext_vector_type(4))) fx4;

// ---------------- resize along W: (3,2160,3840) -> (3,2160,256) ----------------
__global__ void resize_w_kernel(const float* __restrict__ img, float* __restrict__ tmp) {
  __shared__ __align__(16) float row[3840];
  const int bh = blockIdx.x;            // c*2160 + h
  const float* src = img + (size_t)bh * 3840;
  const int tid = threadIdx.x;          // 256
  const float4* s4 = (const float4*)src;
  float4* r4 = (float4*)row;
  for (int i = tid; i < 960; i += 256) r4[i] = s4[i];
  __syncthreads();
  const int i = tid;
  const int center = 15*i + 7;
  int lo = center - 14; if (lo < 0) lo = 0;
  int hi = center + 14; if (hi > 3839) hi = 3839;
  float acc = 0.f, wsum = 0.f;
  for (int j = lo; j <= hi; ++j) {
    int d = center - j; d = d < 0 ? -d : d;
    float w = (float)(15 - d);
    acc += w * row[j];
    wsum += w;
  }
  tmp[bh*256 + i] = acc / wsum;
}

// ---------------- resize along H: (3,2160,256) -> (3,256,256) ----------------
__global__ void resize_h_kernel(const float* __restrict__ tmp, float* __restrict__ dst) {
  const int c = blockIdx.x >> 8;
  const int oh = blockIdx.x & 255;
  const int ow = threadIdx.x;           // 256
  const float sf = ((float)oh + 0.5f) * 8.4375f - 0.5f;
  int lo = (int)ceilf(sf - 8.4375f); if (lo < 0) lo = 0;
  int hi = (int)floorf(sf + 8.4375f); if (hi > 2159) hi = 2159;
  float acc = 0.f, wsum = 0.f;
  for (int j = lo; j <= hi; ++j) {
    float w = 1.f - fabsf(sf - (float)j) * (16.f/135.f);
    if (w > 0.f) {
      acc += w * tmp[(c*2160 + j)*256 + ow];
      wsum += w;
    }
  }
  dst[blockIdx.x*256 + ow] = acc / wsum;
}

// ---------------- fused conv3x3(s2,p1) + input-norm-on-stage + lrelu + stats ----------------
template<int CIN,int CICHUNK,int HIN,int WIN,int HOUT,int WOUT,int NPIN,int MODE>
__global__ __launch_bounds__(256) void conv_fused(
    const float* __restrict__ in, const float* __restrict__ wt, const float* __restrict__ bias,
    const float* __restrict__ pin, const float* __restrict__ gin, const float* __restrict__ bin,
    float* __restrict__ out, float* __restrict__ pout,
    const float* __restrict__ gself, const float* __restrict__ bself) {
  constexpr int NTW = WOUT/16;
  constexpr int NT  = (HOUT/16)*NTW;
  constexpr int NCHUNK = CIN/CICHUNK;
  constexpr int SLOTS = CICHUNK*33*9;          // float4 slots per chunk
  constexpr float PHW_INV = 1.f/(float)(HIN*WIN); // producer spatial size

  __shared__ float sx[CICHUNK*33*36];
  __shared__ float wl[CIN*9];
  __shared__ float sA[CIN], sB[CIN];
  __shared__ float2 red2[256];

  const int co = blockIdx.x / NT;
  const int t  = blockIdx.x % NT;
  const int oh0 = (t / NTW)*16, ow0 = (t % NTW)*16;
  const int tid = threadIdx.x;

  for (int i = tid; i < CIN*9; i += 256) wl[i] = wt[co*CIN*9 + i];
  if (NPIN > 0) {
    if (tid < CIN) {
      const float2* p2 = (const float2*)pin;
      float s = 0.f, q = 0.f;
      #pragma unroll 4
      for (int k = 0; k < NPIN; ++k) { float2 p = p2[tid*NPIN + k]; s += p.x; q += p.y; }
      const float m = s * PHW_INV;
      float var = q * PHW_INV - m*m; var = fmaxf(var, 0.f);
      const float A = gin[tid] * rsqrtf(var + EPS);
      sA[tid] = A; sB[tid] = bin[tid] - m*A;
    }
  }
  __syncthreads();

  const int ohl = tid >> 4, owl = tid & 15;
  float acc = bias[co];

  for (int cc = 0; cc < NCHUNK; ++cc) {
    if (cc) __syncthreads();
    const int cb = cc*CICHUNK;
    for (int i = tid; i < SLOTS; i += 256) {
      const int ci_l = i / 297;
      const int rem  = i - ci_l*297;
      const int r = rem / 9, q = rem - r*9;
      const int grow = 2*oh0 - 1 + r;
      const int ga   = 2*ow0 - 4 + 4*q;
      float4 v = make_float4(0.f,0.f,0.f,0.f);
      if (grow >= 0 && grow < HIN && ga >= 0) {
        v = *(const float4*)(in + ((size_t)(cb+ci_l)*HIN + grow)*WIN + ga);
        if (NPIN > 0) {
          const float A = sA[cb+ci_l], B = sB[cb+ci_l];
          v.x = fmaf(A, v.x, B); v.y = fmaf(A, v.y, B);
          v.z = fmaf(A, v.z, B); v.w = fmaf(A, v.w, B);
        }
      }
      *(float4*)&sx[(ci_l*33 + r)*36 + q*4] = v;
    }
    __syncthreads();
    #pragma unroll 4
    for (int ci_l = 0; ci_l < CICHUNK; ++ci_l) {
      const float* sp = sx + ci_l*1188;
      const float* wp = wl + (cb+ci_l)*9;
      #pragma unroll
      for (int kh = 0; kh < 3; ++kh) {
        const float* rp = sp + (2*ohl + kh)*36 + 3 + 2*owl;
        acc = fmaf(rp[0], wp[kh*3+0], acc);
        acc = fmaf(rp[1], wp[kh*3+1], acc);
        acc = fmaf(rp[2], wp[kh*3+2], acc);
      }
    }
  }

  acc = acc >= 0.f ? acc : 0.2f*acc;
  out[(size_t)co*HOUT*WOUT + (oh0+ohl)*WOUT + ow0 + owl] = acc;

  // stats
  red2[tid] = make_float2(acc, acc*acc);
  __syncthreads();
  for (int s = 128; s > 0; s >>= 1) {
    if (tid < s) { red2[tid].x += red2[tid+s].x; red2[tid].y += red2[tid+s].y; }
    __syncthreads();
  }
  if (tid == 0) {
    if (MODE == 1) {
      ((float2*)pout)[co*NT + t] = red2[0];
    } else { // MODE 2: whole channel in block
      const float m = red2[0].x / (float)(HOUT*WOUT);
      float var = red2[0].y / (float)(HOUT*WOUT) - m*m; var = fmaxf(var, 0.f);
      const float A = gself[co] * rsqrtf(var + EPS);
      pout[co*2]   = A;
      pout[co*2+1] = bself[co] - m*A;
    }
  }
}

// ---------------- conv5 (128ci,16x16 -> 1co,8x8) + lrelu + w6 dot partials ----------------
__global__ __launch_bounds__(256) void conv5_fused(const float* __restrict__ in,
    const float* __restrict__ wt, const float* __restrict__ bias,
    const float* __restrict__ ab4, const float* __restrict__ w6,
    float* __restrict__ part) {
  __shared__ float sx[32*17*20];
  __shared__ float wl[128*9];
  __shared__ float sA[128], sB[128];
  __shared__ float red[256];
  const int co = blockIdx.x;
  const int tid = threadIdx.x;
  for (int i = tid; i < 1152; i += 256) wl[i] = wt[co*1152 + i];
  if (tid < 128) { sA[tid] = ab4[tid*2]; sB[tid] = ab4[tid*2+1]; }
  __syncthreads();

  const int px = tid & 63, q = tid >> 6;
  const int ohl = px >> 3, owl = px & 7;
  float acc = 0.f;
  for (int cc = 0; cc < 4; ++cc) {
    if (cc) __syncthreads();
    const int cb = cc*32;
    for (int i = tid; i < 32*17*5; i += 256) {   // 2720 float4 slots
      const int ci_l = i / 85;
      const int rem  = i - ci_l*85;
      const int r = rem / 5, qq = rem - r*5;
      const int grow = r - 1;
      const int ga   = 4*qq - 4;
      float4 v = make_float4(0.f,0.f,0.f,0.f);
      if (grow >= 0 && grow < 16 && ga >= 0) {
        v = *(const float4*)(in + ((size_t)(cb+ci_l)*16 + grow)*16 + ga);
        const float A = sA[cb+ci_l], B = sB[cb+ci_l];
        v.x = fmaf(A, v.x, B); v.y = fmaf(A, v.y, B);
        v.z = fmaf(A, v.z, B); v.w = fmaf(A, v.w, B);
      }
      *(float4*)&sx[(ci_l*17 + r)*20 + qq*4] = v;
    }
    __syncthreads();
    #pragma unroll 2
    for (int k = 0; k < 8; ++k) {
      const int ci_l = q*8 + k;
      const float* sp = sx + ci_l*340;
      const float* wp = wl + (cb+ci_l)*9;
      #pragma unroll
      for (int kh = 0; kh < 3; ++kh) {
        const float* rp = sp + (2*ohl + kh)*20 + 3 + 2*owl;
        acc = fmaf(rp[0], wp[kh*3+0], acc);
        acc = fmaf(rp[1], wp[kh*3+1], acc);
        acc = fmaf(rp[2], wp[kh*3+2], acc);
      }
    }
  }
  red[tid] = acc;
  __syncthreads();
  if (tid < 64) {
    float a = red[tid] + red[tid+64] + red[tid+128] + red[tid+192] + bias[co];
    a = a >= 0.f ? a : 0.2f*a;
    #pragma unroll
    for (int j = 0; j < 3; ++j) {
      float v = a * w6[(j*128 + co)*64 + tid];
      #pragma unroll
      for (int off = 32; off > 0; off >>= 1) v += __shfl_down(v, off);
      if (tid == 0) part[co*3 + j] = v;
    }
  }
}

// ---------------- blend + pack: flp[c*35936+j] = bf16(fl[j]) | bf16(fl[j+1])<<16 ----------------
__global__ __launch_bounds__(256) void blend_pack_kernel(const float* __restrict__ l0,
    const float* __restrict__ l1, const float* __restrict__ l2,
    const float* __restrict__ part, const float* __restrict__ b6,
    unsigned* __restrict__ flp) {
  __shared__ float sp[3];
  const int tid = threadIdx.x;
  if (tid < 3) {
    float s = b6[tid];
    #pragma unroll 16
    for (int k = 0; k < 128; ++k) s += part[k*3 + tid];
    sp[tid] = s;
  }
  __syncthreads();
  const int i = blockIdx.x*256 + tid;
  if (i >= 3*35936) return;
  const int c = i / 35936, j = i - c*35936;
  const int src = c*35937 + j;
  const float v0 = sp[0]*l0[src]   + sp[1]*l1[src]   + sp[2]*l2[src];
  const float v1 = sp[0]*l0[src+1] + sp[1]*l1[src+1] + sp[2]*l2[src+1];
  unsigned u0 = __float_as_uint(v0); u0 = (u0 + 0x7fffu + ((u0>>16)&1u)) >> 16;
  unsigned u1 = __float_as_uint(v1); u1 = (u1 + 0x7fffu + ((u1>>16)&1u)) >> 16;
  flp[c*35936 + j] = u0 | (u1 << 16);
}

// ---------------- trilinear: LDS-staged packed LUT, 4 px/thread/iter, nt stores ----------------
__global__ __launch_bounds__(1024) void trilinear_kernel(const float* __restrict__ img,
    const unsigned* __restrict__ flp, float* __restrict__ out) {
  __shared__ unsigned slut[35936];
  const int tid = threadIdx.x;
  const int p0 = blockIdx.x * 32400;     // 256 blocks * 32400 = 8,294,400 exactly
  for (int c = 0; c < 3; ++c) {
    if (c) __syncthreads();
    for (int i = tid; i < 35936; i += 1024) slut[i] = flp[c*35936 + i];
    __syncthreads();
    for (int g = tid; g < 8100; g += 1024) {
      const int p = p0 + 4*g;
      const float4 rr = *(const float4*)(img + p);
      const float4 gg = *(const float4*)(img + NPX + p);
      const float4 bb = *(const float4*)(img + 2*NPX + p);
      const float rv[4] = {rr.x, rr.y, rr.z, rr.w};
      const float gv[4] = {gg.x, gg.y, gg.z, gg.w};
      const float bv[4] = {bb.x, bb.y, bb.z, bb.w};
      float ov[4];
      #pragma unroll
      for (int k = 0; k < 4; ++k) {
        const float xr = rv[k]*32.f, xg = gv[k]*32.f, xb = bv[k]*32.f;
        int ir = (int)xr; ir = ir > 31 ? 31 : ir;
        int ig = (int)xg; ig = ig > 31 ? 31 : ig;
        int ib = (int)xb; ib = ib > 31 ? 31 : ib;
        const float fr = xr - (float)ir;
        const float fg = xg - (float)ig;
        const float fb = xb - (float)ib;
        const int base = (ib*33 + ig)*33 + ir;
        const unsigned p00 = slut[base],      p01 = slut[base+33];
        const unsigned p10 = slut[base+1089], p11 = slut[base+1122];
        const float v000 = __uint_as_float(p00 << 16), v001 = __uint_as_float(p00 & 0xffff0000u);
        const float v010 = __uint_as_float(p01 << 16), v011 = __uint_as_float(p01 & 0xffff0000u);
        const float v100 = __uint_as_float(p10 << 16), v101 = __uint_as_float(p10 & 0xffff0000u);
        const float v110 = __uint_as_float(p11 << 16), v111 = __uint_as_float(p11 & 0xffff0000u);
        const float a0 = fmaf(fr, v001 - v000, v000);
        const float a1 = fmaf(fr, v011 - v010, v010);
        const float a2 = fmaf(fr, v101 - v100, v100);
        const float a3 = fmaf(fr, v111 - v110, v110);
        const float lo = fmaf(fg, a1 - a0, a0);
        const float hi = fmaf(fg, a3 - a2, a2);
        ov[k] = fmaf(fb, hi - lo, lo);
      }
      fx4 res = {ov[0], ov[1], ov[2], ov[3]};
      __builtin_nontemporal_store(res, (fx4*)(out + (size_t)c*NPX + p));
    }
  }
}

extern "C" void kernel_launch(void* const* d_in, const int* in_sizes, int n_in,
                              void* d_out, int out_size, void* d_ws, size_t ws_size,
                              hipStream_t stream) {
  const float* img  = (const float*)d_in[0];
  const float* lut0 = (const float*)d_in[1];
  const float* lut1 = (const float*)d_in[2];
  const float* lut2 = (const float*)d_in[3];
  const float* w1 = (const float*)d_in[4];  const float* b1  = (const float*)d_in[5];
  const float* g1 = (const float*)d_in[6];  const float* be1 = (const float*)d_in[7];
  const float* w2 = (const float*)d_in[8];  const float* b2  = (const float*)d_in[9];
  const float* g2 = (const float*)d_in[10]; const float* be2 = (const float*)d_in[11];
  const float* w3 = (const float*)d_in[12]; const float* b3  = (const float*)d_in[13];
  const float* g3 = (const float*)d_in[14]; const float* be3 = (const float*)d_in[15];
  const float* w4 = (const float*)d_in[16]; const float* b4  = (const float*)d_in[17];
  const float* g4 = (const float*)d_in[18]; const float* be4 = (const float*)d_in[19];
  const float* w5 = (const float*)d_in[20]; const float* b5  = (const float*)d_in[21];
  const float* w6 = (const float*)d_in[22]; const float* b6  = (const float*)d_in[23];

  float* ws = (float*)d_ws;
  float* tmp   = ws;                 // 3*2160*256 = 1,658,880 (dead after resize_h)
  float* r256  = ws + 1658880;       // 3*256*256 = 196,608
  float* c1    = ws;                 // 16*128*128 = 262,144 (tmp dead)
  float* c2    = ws + 262144;        // 32*64*64  = 131,072
  float* c3    = ws + 393216;        // 64*32*32  =  65,536
  float* c4    = ws + 458752;        // 128*16*16 =  32,768
  float* part1 = ws + 491520;        // 16*64*2  = 2048
  float* part2 = ws + 493568;        // 32*16*2  = 1024
  float* part3 = ws + 494592;        // 64*4*2   = 512
  float* ab4   = ws + 495104;        // 128*2    = 256
  float* part6 = ws + 495360;        // 128*3    = 384 (pad to 512)
  unsigned* flp = (unsigned*)(ws + 495872); // 3*35936 = 107,808 dwords

  resize_w_kernel<<<3*2160, 256, 0, stream>>>(img, tmp);
  resize_h_kernel<<<3*256, 256, 0, stream>>>(tmp, r256);

  conv_fused< 3, 3,256,256,128,128, 0,1><<<16*64, 256, 0, stream>>>(
      r256, w1, b1, nullptr, nullptr, nullptr, c1, part1, nullptr, nullptr);
  conv_fused<16,16,128,128, 64, 64,64,1><<<32*16, 256, 0, stream>>>(
      c1, w2, b2, part1, g1, be1, c2, part2, nullptr, nullptr);
  conv_fused<32,32, 64, 64, 32, 32,16,1><<<64*4, 256, 0, stream>>>(
      c2, w3, b3, part2, g2, be2, c3, part3, nullptr, nullptr);
  conv_fused<64,32, 32, 32, 16, 16, 4,2><<<128, 256, 0, stream>>>(
      c3, w4, b4, part3, g3, be3, c4, ab4, g4, be4);
  conv5_fused<<<128, 256, 0, stream>>>(c4, w5, b5, ab4, w6, part6);

  blend_pack_kernel<<<422, 256, 0, stream>>>(lut0, lut1, lut2, part6, b6, flp);
  trilinear_kernel<<<256, 1024, 0, stream>>>(img, flp, (float*)d_out);
}

// Round 7
// 194.386 us; speedup vs baseline: 2.4755x; 1.0225x over previous
//
#include <hip/hip_runtime.h>

#define NPX (2160*3840)
#define EPS 1e-5f

typedef float __attribute__((ext_vector_type(4))) fx4;

// ---------------- resize along W: (3,2160,3840) -> (3,2160,256) ----------------
// sample center = 15*i+7 (exact int); 29 taps, weights 15-|d|; wsum=225 (197 at edges).
__global__ __launch_bounds__(256) void resize_w_kernel(const float* __restrict__ img,
                                                       float* __restrict__ tmp) {
  __shared__ __align__(16) float row[3872];   // 16 zero | 3840 | 16 zero
  const int bh = blockIdx.x;            // c*2160 + h
  const float* src = img + (size_t)bh * 3840;
  const int tid = threadIdx.x;          // 256
  if (tid < 16) { row[tid] = 0.f; row[3856 + tid] = 0.f; }
  const float4* s4 = (const float4*)src;
  float4* r4 = (float4*)(row + 16);
  for (int i = tid; i < 960; i += 256) r4[i] = s4[i];
  __syncthreads();
  const int i = tid;
  const float* rp = row + 15*i + 9;     // = 16 + center-14
  float acc = 0.f;
  #pragma unroll
  for (int k = 0; k < 29; ++k) {
    const float w = (float)(15 - (k < 14 ? 14 - k : k - 14));
    acc = fmaf(w, rp[k], acc);
  }
  const float rcpw = (i == 0 || i == 255) ? (1.f/197.f) : (1.f/225.f);
  tmp[bh*256 + i] = acc * rcpw;
}

// ---------------- resize along H: (3,2160,256) -> (3,256,256) ----------------
__global__ __launch_bounds__(256) void resize_h_kernel(const float* __restrict__ tmp,
                                                       float* __restrict__ dst) {
  const int c = blockIdx.x >> 8;
  const int oh = blockIdx.x & 255;
  const int ow = threadIdx.x;           // 256
  const float sf = ((float)oh + 0.5f) * 8.4375f - 0.5f;
  int lo = (int)ceilf(sf - 8.4375f); if (lo < 0) lo = 0;
  int hi = (int)floorf(sf + 8.4375f); if (hi > 2159) hi = 2159;
  float acc = 0.f, wsum = 0.f;
  for (int j = lo; j <= hi; ++j) {
    const float w = 1.f - fabsf(sf - (float)j) * (16.f/135.f);
    acc = fmaf(w, tmp[(c*2160 + j)*256 + ow], acc);
    wsum += w;
  }
  dst[blockIdx.x*256 + ow] = acc / wsum;
}

// ---------------- fused conv3x3(s2,p1) + input-norm-on-stage + lrelu + stats ----------------
template<int CIN,int CICHUNK,int HIN,int WIN,int HOUT,int WOUT,int NPIN,int MODE>
__global__ __launch_bounds__(256) void conv_fused(
    const float* __restrict__ in, const float* __restrict__ wt, const float* __restrict__ bias,
    const float* __restrict__ pin, const float* __restrict__ gin, const float* __restrict__ bin,
    float* __restrict__ out, float* __restrict__ pout,
    const float* __restrict__ gself, const float* __restrict__ bself) {
  constexpr int NTW = WOUT/16;
  constexpr int NT  = (HOUT/16)*NTW;
  constexpr int NCHUNK = CIN/CICHUNK;
  constexpr int SLOTS = CICHUNK*33*9;          // float4 slots per chunk
  constexpr float PHW_INV = 1.f/(float)(HIN*WIN); // producer spatial size

  __shared__ float sx[CICHUNK*33*36];
  __shared__ float wl[CIN*9];
  __shared__ float sA[CIN], sB[CIN];
  __shared__ float2 wred[4];

  const int co = blockIdx.x / NT;
  const int t  = blockIdx.x % NT;
  const int oh0 = (t / NTW)*16, ow0 = (t % NTW)*16;
  const int tid = threadIdx.x;

  for (int i = tid; i < CIN*9; i += 256) wl[i] = wt[co*CIN*9 + i];
  if (NPIN > 0) {
    if (tid < CIN) {
      const float2* p2 = (const float2*)pin;
      float s = 0.f, q = 0.f;
      #pragma unroll 4
      for (int k = 0; k < NPIN; ++k) { float2 p = p2[tid*NPIN + k]; s += p.x; q += p.y; }
      const float m = s * PHW_INV;
      float var = q * PHW_INV - m*m; var = fmaxf(var, 0.f);
      const float A = gin[tid] * rsqrtf(var + EPS);
      sA[tid] = A; sB[tid] = bin[tid] - m*A;
    }
  }
  __syncthreads();

  const int ohl = tid >> 4, owl = tid & 15;
  float acc = bias[co];

  for (int cc = 0; cc < NCHUNK; ++cc) {
    if (cc) __syncthreads();
    const int cb = cc*CICHUNK;
    for (int i = tid; i < SLOTS; i += 256) {
      const int ci_l = i / 297;
      const int rem  = i - ci_l*297;
      const int r = rem / 9, q = rem - r*9;
      const int grow = 2*oh0 - 1 + r;
      const int ga   = 2*ow0 - 4 + 4*q;
      float4 v = make_float4(0.f,0.f,0.f,0.f);
      if (grow >= 0 && grow < HIN && ga >= 0) {
        v = *(const float4*)(in + ((size_t)(cb+ci_l)*HIN + grow)*WIN + ga);
        if (NPIN > 0) {
          const float A = sA[cb+ci_l], B = sB[cb+ci_l];
          v.x = fmaf(A, v.x, B); v.y = fmaf(A, v.y, B);
          v.z = fmaf(A, v.z, B); v.w = fmaf(A, v.w, B);
        }
      }
      *(float4*)&sx[(ci_l*33 + r)*36 + q*4] = v;
    }
    __syncthreads();
    #pragma unroll 4
    for (int ci_l = 0; ci_l < CICHUNK; ++ci_l) {
      const float* sp = sx + ci_l*1188;
      const float* wp = wl + (cb+ci_l)*9;
      #pragma unroll
      for (int kh = 0; kh < 3; ++kh) {
        const float* rp = sp + (2*ohl + kh)*36 + 3 + 2*owl;
        acc = fmaf(rp[0], wp[kh*3+0], acc);
        acc = fmaf(rp[1], wp[kh*3+1], acc);
        acc = fmaf(rp[2], wp[kh*3+2], acc);
      }
    }
  }

  acc = acc >= 0.f ? acc : 0.2f*acc;
  out[(size_t)co*HOUT*WOUT + (oh0+ohl)*WOUT + ow0 + owl] = acc;

  // stats: wave shfl reduce, 1 barrier
  float s = acc, q = acc*acc;
  #pragma unroll
  for (int off = 32; off > 0; off >>= 1) {
    s += __shfl_down(s, off);
    q += __shfl_down(q, off);
  }
  if ((tid & 63) == 0) wred[tid >> 6] = make_float2(s, q);
  __syncthreads();
  if (tid == 0) {
    const float S = wred[0].x + wred[1].x + wred[2].x + wred[3].x;
    const float Q = wred[0].y + wred[1].y + wred[2].y + wred[3].y;
    if (MODE == 1) {
      ((float2*)pout)[co*NT + t] = make_float2(S, Q);
    } else { // MODE 2: whole channel in block
      const float m = S / (float)(HOUT*WOUT);
      float var = Q / (float)(HOUT*WOUT) - m*m; var = fmaxf(var, 0.f);
      const float A = gself[co] * rsqrtf(var + EPS);
      pout[co*2]   = A;
      pout[co*2+1] = bself[co] - m*A;
    }
  }
}

// ---------------- conv5 (128ci,16x16 -> 1co,8x8) + lrelu + w6 dot partials ----------------
__global__ __launch_bounds__(256) void conv5_fused(const float* __restrict__ in,
    const float* __restrict__ wt, const float* __restrict__ bias,
    const float* __restrict__ ab4, const float* __restrict__ w6,
    float* __restrict__ part) {
  __shared__ float sx[32*17*20];
  __shared__ float wl[128*9];
  __shared__ float sA[128], sB[128];
  __shared__ float red[256];
  const int co = blockIdx.x;
  const int tid = threadIdx.x;
  for (int i = tid; i < 1152; i += 256) wl[i] = wt[co*1152 + i];
  if (tid < 128) { sA[tid] = ab4[tid*2]; sB[tid] = ab4[tid*2+1]; }
  __syncthreads();

  const int px = tid & 63, q = tid >> 6;
  const int ohl = px >> 3, owl = px & 7;
  float acc = 0.f;
  for (int cc = 0; cc < 4; ++cc) {
    if (cc) __syncthreads();
    const int cb = cc*32;
    for (int i = tid; i < 32*17*5; i += 256) {   // 2720 float4 slots
      const int ci_l = i / 85;
      const int rem  = i - ci_l*85;
      const int r = rem / 5, qq = rem - r*5;
      const int grow = r - 1;
      const int ga   = 4*qq - 4;
      float4 v = make_float4(0.f,0.f,0.f,0.f);
      if (grow >= 0 && grow < 16 && ga >= 0) {
        v = *(const float4*)(in + ((size_t)(cb+ci_l)*16 + grow)*16 + ga);
        const float A = sA[cb+ci_l], B = sB[cb+ci_l];
        v.x = fmaf(A, v.x, B); v.y = fmaf(A, v.y, B);
        v.z = fmaf(A, v.z, B); v.w = fmaf(A, v.w, B);
      }
      *(float4*)&sx[(ci_l*17 + r)*20 + qq*4] = v;
    }
    __syncthreads();
    #pragma unroll 2
    for (int k = 0; k < 8; ++k) {
      const int ci_l = q*8 + k;
      const float* sp = sx + ci_l*340;
      const float* wp = wl + (cb+ci_l)*9;
      #pragma unroll
      for (int kh = 0; kh < 3; ++kh) {
        const float* rp = sp + (2*ohl + kh)*20 + 3 + 2*owl;
        acc = fmaf(rp[0], wp[kh*3+0], acc);
        acc = fmaf(rp[1], wp[kh*3+1], acc);
        acc = fmaf(rp[2], wp[kh*3+2], acc);
      }
    }
  }
  red[tid] = acc;
  __syncthreads();
  if (tid < 64) {
    float a = red[tid] + red[tid+64] + red[tid+128] + red[tid+192] + bias[co];
    a = a >= 0.f ? a : 0.2f*a;
    #pragma unroll
    for (int j = 0; j < 3; ++j) {
      float v = a * w6[(j*128 + co)*64 + tid];
      #pragma unroll
      for (int off = 32; off > 0; off >>= 1) v += __shfl_down(v, off);
      if (tid == 0) part[co*3 + j] = v;
    }
  }
}

// ---------------- blend + pack: flp[c*35936+j] = bf16(fl[j]) | bf16(fl[j+1])<<16 ----------------
__global__ __launch_bounds__(256) void blend_pack_kernel(const float* __restrict__ l0,
    const float* __restrict__ l1, const float* __restrict__ l2,
    const float* __restrict__ part, const float* __restrict__ b6,
    unsigned* __restrict__ flp) {
  __shared__ float sred[2][3];
  __shared__ float sp[3];
  const int tid = threadIdx.x;
  // parallel pred reduction over 128 lanes (2 waves)
  float a0 = 0.f, a1 = 0.f, a2 = 0.f;
  if (tid < 128) { a0 = part[tid*3]; a1 = part[tid*3+1]; a2 = part[tid*3+2]; }
  #pragma unroll
  for (int off = 32; off > 0; off >>= 1) {
    a0 += __shfl_down(a0, off);
    a1 += __shfl_down(a1, off);
    a2 += __shfl_down(a2, off);
  }
  if (tid < 128 && (tid & 63) == 0) {
    sred[tid >> 6][0] = a0; sred[tid >> 6][1] = a1; sred[tid >> 6][2] = a2;
  }
  __syncthreads();
  if (tid < 3) sp[tid] = sred[0][tid] + sred[1][tid] + b6[tid];
  __syncthreads();
  const int i = blockIdx.x*256 + tid;
  if (i >= 3*35936) return;
  const int c = i / 35936, j = i - c*35936;
  const int src = c*35937 + j;
  const float v0 = sp[0]*l0[src]   + sp[1]*l1[src]   + sp[2]*l2[src];
  const float v1 = sp[0]*l0[src+1] + sp[1]*l1[src+1] + sp[2]*l2[src+1];
  unsigned u0 = __float_as_uint(v0); u0 = (u0 + 0x7fffu + ((u0>>16)&1u)) >> 16;
  unsigned u1 = __float_as_uint(v1); u1 = (u1 + 0x7fffu + ((u1>>16)&1u)) >> 16;
  flp[c*35936 + j] = u0 | (u1 << 16);
}

// ---------------- trilinear: LDS-staged packed LUT, 4 px/thread/iter, nt stores ----------------
__global__ __launch_bounds__(1024) void trilinear_kernel(const float* __restrict__ img,
    const unsigned* __restrict__ flp, float* __restrict__ out) {
  __shared__ unsigned slut[35936];
  const int tid = threadIdx.x;
  const int p0 = blockIdx.x * 32400;     // 256 blocks * 32400 = 8,294,400 exactly
  for (int c = 0; c < 3; ++c) {
    if (c) __syncthreads();
    {
      uint4* d4 = (uint4*)slut;
      const uint4* s4 = (const uint4*)(flp + c*35936);
      for (int i = tid; i < 8984; i += 1024) d4[i] = s4[i];   // 35936 = 4*8984
    }
    __syncthreads();
    for (int g = tid; g < 8100; g += 1024) {
      const int p = p0 + 4*g;
      const float4 rr = *(const float4*)(img + p);
      const float4 gg = *(const float4*)(img + NPX + p);
      const float4 bb = *(const float4*)(img + 2*NPX + p);
      const float rv[4] = {rr.x, rr.y, rr.z, rr.w};
      const float gv[4] = {gg.x, gg.y, gg.z, gg.w};
      const float bv[4] = {bb.x, bb.y, bb.z, bb.w};
      float ov[4];
      #pragma unroll
      for (int k = 0; k < 4; ++k) {
        const float xr = rv[k]*32.f, xg = gv[k]*32.f, xb = bv[k]*32.f;
        int ir = (int)xr; ir = ir > 31 ? 31 : ir;
        int ig = (int)xg; ig = ig > 31 ? 31 : ig;
        int ib = (int)xb; ib = ib > 31 ? 31 : ib;
        const float fr = xr - (float)ir;
        const float fg = xg - (float)ig;
        const float fb = xb - (float)ib;
        const int base = (ib*33 + ig)*33 + ir;
        const unsigned p00 = slut[base],      p01 = slut[base+33];
        const unsigned p10 = slut[base+1089], p11 = slut[base+1122];
        const float v000 = __uint_as_float(p00 << 16), v001 = __uint_as_float(p00 & 0xffff0000u);
        const float v010 = __uint_as_float(p01 << 16), v011 = __uint_as_float(p01 & 0xffff0000u);
        const float v100 = __uint_as_float(p10 << 16), v101 = __uint_as_float(p10 & 0xffff0000u);
        const float v110 = __uint_as_float(p11 << 16), v111 = __uint_as_float(p11 & 0xffff0000u);
        const float a0 = fmaf(fr, v001 - v000, v000);
        const float a1 = fmaf(fr, v011 - v010, v010);
        const float a2 = fmaf(fr, v101 - v100, v100);
        const float a3 = fmaf(fr, v111 - v110, v110);
        const float lo = fmaf(fg, a1 - a0, a0);
        const float hi = fmaf(fg, a3 - a2, a2);
        ov[k] = fmaf(fb, hi - lo, lo);
      }
      fx4 res = {ov[0], ov[1], ov[2], ov[3]};
      __builtin_nontemporal_store(res, (fx4*)(out + (size_t)c*NPX + p));
    }
  }
}

extern "C" void kernel_launch(void* const* d_in, const int* in_sizes, int n_in,
                              void* d_out, int out_size, void* d_ws, size_t ws_size,
                              hipStream_t stream) {
  const float* img  = (const float*)d_in[0];
  const float* lut0 = (const float*)d_in[1];
  const float* lut1 = (const float*)d_in[2];
  const float* lut2 = (const float*)d_in[3];
  const float* w1 = (const float*)d_in[4];  const float* b1  = (const float*)d_in[5];
  const float* g1 = (const float*)d_in[6];  const float* be1 = (const float*)d_in[7];
  const float* w2 = (const float*)d_in[8];  const float* b2  = (const float*)d_in[9];
  const float* g2 = (const float*)d_in[10]; const float* be2 = (const float*)d_in[11];
  const float* w3 = (const float*)d_in[12]; const float* b3  = (const float*)d_in[13];
  const float* g3 = (const float*)d_in[14]; const float* be3 = (const float*)d_in[15];
  const float* w4 = (const float*)d_in[16]; const float* b4  = (const float*)d_in[17];
  const float* g4 = (const float*)d_in[18]; const float* be4 = (const float*)d_in[19];
  const float* w5 = (const float*)d_in[20]; const float* b5  = (const float*)d_in[21];
  const float* w6 = (const float*)d_in[22]; const float* b6  = (const float*)d_in[23];

  float* ws = (float*)d_ws;
  float* tmp   = ws;                 // 3*2160*256 = 1,658,880 (dead after resize_h)
  float* r256  = ws + 1658880;       // 3*256*256 = 196,608
  float* c1    = ws;                 // 16*128*128 = 262,144 (tmp dead)
  float* c2    = ws + 262144;        // 32*64*64  = 131,072
  float* c3    = ws + 393216;        // 64*32*32  =  65,536
  float* c4    = ws + 458752;        // 128*16*16 =  32,768
  float* part1 = ws + 491520;        // 16*64*2  = 2048
  float* part2 = ws + 493568;        // 32*16*2  = 1024
  float* part3 = ws + 494592;        // 64*4*2   = 512
  float* ab4   = ws + 495104;        // 128*2    = 256
  float* part6 = ws + 495360;        // 128*3    = 384 (pad to 512)
  unsigned* flp = (unsigned*)(ws + 495872); // 3*35936 = 107,808 dwords

  resize_w_kernel<<<3*2160, 256, 0, stream>>>(img, tmp);
  resize_h_kernel<<<3*256, 256, 0, stream>>>(tmp, r256);

  conv_fused< 3, 3,256,256,128,128, 0,1><<<16*64, 256, 0, stream>>>(
      r256, w1, b1, nullptr, nullptr, nullptr, c1, part1, nullptr, nullptr);
  conv_fused<16,16,128,128, 64, 64,64,1><<<32*16, 256, 0, stream>>>(
      c1, w2, b2, part1, g1, be1, c2, part2, nullptr, nullptr);
  conv_fused<32,32, 64, 64, 32, 32,16,1><<<64*4, 256, 0, stream>>>(
      c2, w3, b3, part2, g2, be2, c3, part3, nullptr, nullptr);
  conv_fused<64,32, 32, 32, 16, 16, 4,2><<<128, 256, 0, stream>>>(
      c3, w4, b4, part3, g3, be3, c4, ab4, g4, be4);
  conv5_fused<<<128, 256, 0, stream>>>(c4, w5, b5, ab4, w6, part6);

  blend_pack_kernel<<<422, 256, 0, stream>>>(lut0, lut1, lut2, part6, b6, flp);
  trilinear_kernel<<<256, 1024, 0, stream>>>(img, flp, (float*)d_out);
}